// Round 5
// baseline (230.895 us; speedup 1.0000x reference)
//
#include <hip/hip_runtime.h>

#define HH 128
#define WW 128
#define HW (HH * WW)
#define CIN 64
#define COUT 64

// ws layout (bytes):
//   Bf  : [0, 49152)        main-conv B-frags bf16 [pk6][kc2][nt4][lane64][j8]
//   OBf : [49152, +18432)   offset-conv B-frags bf16 [s18][lane64][j8]
#define BF_OFF  0
#define OBF_OFF 49152

typedef short bf16x8 __attribute__((ext_vector_type(8)));
typedef float f32x4 __attribute__((ext_vector_type(4)));

__device__ __forceinline__ unsigned short f2bf(float f) {
    union { float f; unsigned int u; } v; v.f = f;
    unsigned int r = v.u + 0x7FFFu + ((v.u >> 16) & 1u);   // RNE
    return (unsigned short)(r >> 16);
}

// -------------------------------------------------------------------------
// Prep: build bf16 B-fragments for both matmuls.
// Main: n=o (64, 4 n-tiles), k = kc*32 + q*8 + j -> channel within tap pk.
// Offset: n=j_out (16, 6 used), K=576: k-step s -> tap=s>>1, chalf=s&1,
//         c = chalf*32 + q*8 + j.
// -------------------------------------------------------------------------
__global__ __launch_bounds__(256) void prep_kernel(const float* __restrict__ ow,
                                                   const float* __restrict__ wh,
                                                   const float* __restrict__ wv,
                                                   unsigned short* __restrict__ Bf,
                                                   unsigned short* __restrict__ OBf) {
    int i = blockIdx.x * 256 + threadIdx.x;
    if (i < 24576) {
        int j    = i & 7;
        int lane = (i >> 3) & 63;
        int nt   = (i >> 9) & 3;
        int kc   = (i >> 11) & 1;
        int pk   = i >> 12;                    // ph*3+k
        int o = nt * 16 + (lane & 15);
        int c = kc * 32 + (lane >> 4) * 8 + j;
        int k = pk % 3;
        const float* src = (pk < 3) ? wh : wv; // both flatten as (O,C,3)
        Bf[i] = f2bf(src[(o * CIN + c) * 3 + k]);
    } else if (i < 24576 + 9216) {
        int mI   = i - 24576;
        int j    = mI & 7;
        int lane = (mI >> 3) & 63;
        int s    = mI >> 9;                    // 0..17
        int n    = lane & 15;
        int q    = lane >> 4;
        int c    = (s & 1) * 32 + q * 8 + j;
        int tap  = s >> 1;
        int dy   = tap / 3, dx = tap % 3;
        OBf[mI] = (n < 6) ? f2bf(ow[((n * CIN + c) * 3 + dy) * 3 + dx])
                          : (unsigned short)0;
    }
}

// -------------------------------------------------------------------------
// Fused kernel. Block = 4 independent waves; wave = 16 consecutive px of one
// row x 64 outs. No LDS staging of activations: each lane gathers its MFMA
// A-fragment elements directly (lane(q,m): channels q*8+j of pixel m ->
// per-instr 4 quads x 16 coalesced px). One barrier total (offset transpose).
// Phase 1: offset conv as MFMA over K=576 (9 taps x 64 c), N=16 (6 used).
// Phase 2: deformable strip conv as MFMA over K=64 per tap, 6 taps.
// -------------------------------------------------------------------------
__global__ __launch_bounds__(256) void fused_kernel(const float* __restrict__ x,
                                                    const float* __restrict__ obias,
                                                    const unsigned short* __restrict__ Bf,
                                                    const unsigned short* __restrict__ OBf,
                                                    float* __restrict__ out) {
    __shared__ float offT[4 * 16 * 10];      // [wave][px16][j pad10] 2.5 KB

    const int tid  = threadIdx.x;
    const int w    = tid >> 6;
    const int lane = tid & 63;
    const int q    = lane >> 4;
    const int m    = lane & 15;

    const int blk = blockIdx.x;              // b(8) x y(128) x xh(2)
    const int b   = blk >> 8;
    const int y   = (blk & 255) >> 1;
    const int x0w = ((blk & 1) << 6) + (w << 4);   // wave's 16-col strip

    const float* xb = x + (size_t)b * CIN * HW;

    // ---------- phase 1: offset conv (3x3, Cin=64 -> 6) ----------
    f32x4 acc6 = {0.f, 0.f, 0.f, 0.f};
#pragma unroll
    for (int s = 0; s < 18; ++s) {
        const int tap = s >> 1;
        const int dy  = tap / 3 - 1;
        const int dx  = tap % 3 - 1;
        const int cb  = (s & 1) * 32 + q * 8;
        int yy = y + dy;
        int xx = x0w + m + dx;
        bool ok = (yy >= 0) && (yy < HH) && (xx >= 0) && (xx < WW);
        int yc = min(max(yy, 0), HH - 1);
        int xc = min(max(xx, 0), WW - 1);
        const float* p = xb + (size_t)cb * HW + yc * WW + xc;
        union { unsigned short us[8]; bf16x8 v; } af;
#pragma unroll
        for (int j = 0; j < 8; ++j) {
            float v = p[(size_t)j * HW];
            af.us[j] = ok ? f2bf(v) : (unsigned short)0;
        }
        bf16x8 bfr = *(const bf16x8*)&OBf[(s * 64 + lane) * 8];
        acc6 = __builtin_amdgcn_mfma_f32_16x16x32_bf16(af.v, bfr, acc6, 0, 0, 0);
    }
    // C layout: row(px) = q*4+reg, col(j) = m. Transpose to per-pixel order.
    float bias = (m < 6) ? obias[m] : 0.f;
#pragma unroll
    for (int reg = 0; reg < 4; ++reg)
        if (m < 6) offT[(w * 16 + q * 4 + reg) * 10 + m] = acc6[reg] + bias;
    __syncthreads();

    // ---------- phase 2: deformable strip conv ----------
    f32x4 acc[4];
#pragma unroll
    for (int nt = 0; nt < 4; ++nt) acc[nt] = (f32x4){0.f, 0.f, 0.f, 0.f};

    const int xs = x0w + m;
    const int ys = y;

#pragma unroll
    for (int pk = 0; pk < 6; ++pk) {
        const int ph = pk / 3;
        const int k  = pk % 3;
        float o1 = offT[(w * 16 + m) * 10 + pk];

        float wA, wB;
        int idxA, idxB;
        if (ph == 0) {
            // horizontal: py = ys + off (frac), px = xs + k - 1 (int)
            float py  = (float)ys + o1;
            float y0f = floorf(py);
            float wy  = py - y0f;
            int   yi  = (int)y0f;
            bool v0 = (yi >= 0) && (yi <= HH - 1);
            bool v1 = (yi + 1 >= 0) && (yi + 1 <= HH - 1);
            int  pxx = xs + k - 1;
            bool pv  = (pxx >= 0) && (pxx <= WW - 1);
            wA = (pv && v0) ? (1.f - wy) : 0.f;
            wB = (pv && v1) ? wy : 0.f;
            int ra = min(max(yi, 0), HH - 1);
            int rb = min(max(yi + 1, 0), HH - 1);
            int ca = min(max(pxx, 0), WW - 1);
            idxA = ra * WW + ca;
            idxB = rb * WW + ca;
        } else {
            // vertical: py = ys + k - 1 (int), px = xs + off (frac)
            float pxf = (float)xs + o1;
            float x0f = floorf(pxf);
            float wx  = pxf - x0f;
            int   xi  = (int)x0f;
            bool v0 = (xi >= 0) && (xi <= WW - 1);
            bool v1 = (xi + 1 >= 0) && (xi + 1 <= WW - 1);
            int  py = ys + k - 1;
            bool pv = (py >= 0) && (py <= HH - 1);
            wA = (pv && v0) ? (1.f - wx) : 0.f;
            wB = (pv && v1) ? wx : 0.f;
            int ra = min(max(py, 0), HH - 1);
            int ca = min(max(xi, 0), WW - 1);
            int cb2 = min(max(xi + 1, 0), WW - 1);
            idxA = ra * WW + ca;
            idxB = ra * WW + cb2;
        }

#pragma unroll
        for (int kc = 0; kc < 2; ++kc) {
            const int cb = kc * 32 + q * 8;
            const float* pA = xb + (size_t)cb * HW + idxA;
            const float* pB = xb + (size_t)cb * HW + idxB;
            union { unsigned short us[8]; bf16x8 v; } af;
#pragma unroll
            for (int j = 0; j < 8; ++j) {
                float v = wA * pA[(size_t)j * HW] + wB * pB[(size_t)j * HW];
                af.us[j] = f2bf(v);
            }
#pragma unroll
            for (int nt = 0; nt < 4; ++nt) {
                bf16x8 bfr = *(const bf16x8*)&Bf[(((pk * 2 + kc) * 4 + nt) * 64 + lane) * 8];
                acc[nt] = __builtin_amdgcn_mfma_f32_16x16x32_bf16(af.v, bfr, acc[nt], 0, 0, 0);
            }
        }
    }

    // ---------- epilogue: C row(px)=q*4+reg, col(o)=m; float4 stores ----------
#pragma unroll
    for (int nt = 0; nt < 4; ++nt) {
        int o = nt * 16 + m;
        float* op = out + ((size_t)(b * COUT + o) * HH + y) * WW + x0w + q * 4;
        *(f32x4*)op = acc[nt];
    }
}

extern "C" void kernel_launch(void* const* d_in, const int* in_sizes, int n_in,
                              void* d_out, int out_size, void* d_ws, size_t ws_size,
                              hipStream_t stream) {
    const float* x     = (const float*)d_in[0];
    const float* ow    = (const float*)d_in[1];
    const float* obias = (const float*)d_in[2];
    const float* wh    = (const float*)d_in[3];
    const float* wv    = (const float*)d_in[4];
    float* out = (float*)d_out;

    char* ws = (char*)d_ws;
    unsigned short* Bf  = (unsigned short*)(ws + BF_OFF);
    unsigned short* OBf = (unsigned short*)(ws + OBF_OFF);

    prep_kernel<<<dim3(132), dim3(256), 0, stream>>>(ow, wh, wv, Bf, OBf);
    // 2048 blocks: b(8) x row(128) x col-half(2); 4 independent waves/block
    fused_kernel<<<dim3(2048), dim3(256), 0, stream>>>(x, obias, Bf, OBf, out);
}

// Round 6
// 138.825 us; speedup vs baseline: 1.6632x; 1.6632x over previous
//
#include <hip/hip_runtime.h>

#define HH 128
#define WW 128
#define HW (HH * WW)
#define CIN 64
#define COUT 64

// ws layout (bytes):
//   xT  : [0, 16777216)       bf16 NHWC [b8][y128][x128][c64]
//   Bf  : [+0, 49152)         main-conv B-frags bf16 [pk6][kc2][nt4][lane64][j8]
//   OBf : [+49152, +18432)    offset-conv B-frags bf16 [s18][lane64][j8]
#define XT_OFF  0
#define BF_OFF  16777216
#define OBF_OFF (BF_OFF + 49152)

typedef short bf16x8 __attribute__((ext_vector_type(8)));
typedef float f32x4 __attribute__((ext_vector_type(4)));

__device__ __forceinline__ unsigned short f2bf(float f) {
    union { float f; unsigned int u; } v; v.f = f;
    unsigned int r = v.u + 0x7FFFu + ((v.u >> 16) & 1u);   // RNE
    return (unsigned short)(r >> 16);
}
__device__ __forceinline__ float bf2f(unsigned short u) {
    union { unsigned int u; float f; } v; v.u = ((unsigned int)u) << 16;
    return v.f;
}

// -------------------------------------------------------------------------
// Prep: bf16 B-fragments for both matmuls (same layout as verified round 5).
// -------------------------------------------------------------------------
__global__ __launch_bounds__(256) void prep_kernel(const float* __restrict__ ow,
                                                   const float* __restrict__ wh,
                                                   const float* __restrict__ wv,
                                                   unsigned short* __restrict__ Bf,
                                                   unsigned short* __restrict__ OBf) {
    int i = blockIdx.x * 256 + threadIdx.x;
    if (i < 24576) {
        int j    = i & 7;
        int lane = (i >> 3) & 63;
        int nt   = (i >> 9) & 3;
        int kc   = (i >> 11) & 1;
        int pk   = i >> 12;                    // ph*3+k
        int o = nt * 16 + (lane & 15);
        int c = kc * 32 + (lane >> 4) * 8 + j;
        int k = pk % 3;
        const float* src = (pk < 3) ? wh : wv; // both flatten as (O,C,3)
        Bf[i] = f2bf(src[(o * CIN + c) * 3 + k]);
    } else if (i < 24576 + 9216) {
        int mI   = i - 24576;
        int j    = mI & 7;
        int lane = (mI >> 3) & 63;
        int s    = mI >> 9;                    // 0..17
        int n    = lane & 15;
        int q    = lane >> 4;
        int c    = (s & 1) * 32 + q * 8 + j;
        int tap  = s >> 1;
        int dy   = tap / 3, dx = tap % 3;
        OBf[mI] = (n < 6) ? f2bf(ow[((n * CIN + c) * 3 + dy) * 3 + dx])
                          : (unsigned short)0;
    }
}

// -------------------------------------------------------------------------
// Repack: x NCHW fp32 -> xT NHWC bf16 via LDS transpose. Block = (b, y row).
// LDS tile padded to 129 -> 2-way banks only (free). Stores contiguous 16B.
// -------------------------------------------------------------------------
__global__ __launch_bounds__(256) void repack_kernel(const float* __restrict__ x,
                                                     unsigned short* __restrict__ xT) {
    __shared__ float tile[64 * 129];
    const int tid = threadIdx.x;
    const int blk = blockIdx.x;          // y(128) x b(8)
    const int b   = blk & 7;
    const int y   = blk >> 3;

    const float* xb = x + (size_t)b * CIN * HW + y * WW;
    const int tx = tid & 127;
    const int th = tid >> 7;
    for (int c0 = 0; c0 < 64; c0 += 2) {
        int c = c0 + th;
        tile[c * 129 + tx] = xb[(size_t)c * HW + tx];
    }
    __syncthreads();

    unsigned short* ob = xT + ((size_t)b * HW + y * WW) * 64;
#pragma unroll
    for (int it = 0; it < 4; ++it) {
        int e  = it * 256 + tid;
        int h  = e & 7;                  // h fastest -> contiguous stores
        int px = e >> 3;
        union { unsigned short us[8]; uint4 u4; } pkd;
#pragma unroll
        for (int j = 0; j < 8; ++j)
            pkd.us[j] = f2bf(tile[(h * 8 + j) * 129 + px]);
        *(uint4*)&ob[px * 64 + h * 8] = pkd.u4;
    }
}

// -------------------------------------------------------------------------
// Fused kernel. 1024 blocks = (y 128) x (b 8) with b = blk&7 so XCD
// round-robin pins each batch's 2MB xT to one XCD L2. Block = 4 waves,
// wave = 32 px (one row) x 64 outs, no inter-wave dependency (one barrier
// for the per-wave offset transpose only).
// All activation traffic is contiguous bf16x8 (16B/lane, full 64B lines).
// -------------------------------------------------------------------------
__global__ __launch_bounds__(256) void fused_kernel(const unsigned short* __restrict__ xT,
                                                    const float* __restrict__ obias,
                                                    const unsigned short* __restrict__ Bf,
                                                    const unsigned short* __restrict__ OBf,
                                                    float* __restrict__ out) {
    __shared__ float offT[4 * 32 * 9];       // [w][px32][pk pad9] 4.6 KB

    const int tid  = threadIdx.x;
    const int w    = tid >> 6;
    const int lane = tid & 63;
    const int q    = lane >> 4;
    const int m    = lane & 15;

    const int blk = blockIdx.x;              // y(128) x b(8)
    const int b   = blk & 7;
    const int y   = blk >> 3;
    const int x0w = w << 5;                  // wave's 32-col strip

    const unsigned short* xtb = xT + (size_t)b * HW * 64;

    // ---------- phase 1: offset conv (3x3, Cin=64 -> 6) ----------
    f32x4 acc6[2] = {{0.f, 0.f, 0.f, 0.f}, {0.f, 0.f, 0.f, 0.f}};
#pragma unroll
    for (int s = 0; s < 18; ++s) {
        const int tap  = s >> 1;
        const int dy   = tap / 3 - 1;
        const int dx   = tap % 3 - 1;
        const int coff = (s & 1) * 32 + q * 8;
        bf16x8 bfr = *(const bf16x8*)&OBf[(s * 64 + lane) * 8];
#pragma unroll
        for (int mt = 0; mt < 2; ++mt) {
            int yy = y + dy;
            int xx = x0w + mt * 16 + m + dx;
            bool ok = (yy >= 0) && (yy < HH) && (xx >= 0) && (xx < WW);
            int yc = min(max(yy, 0), HH - 1);
            int xc = min(max(xx, 0), WW - 1);
            uint4 raw = *(const uint4*)&xtb[(size_t)(yc * WW + xc) * 64 + coff];
            if (!ok) raw = make_uint4(0, 0, 0, 0);
            union { uint4 u4; bf16x8 v; } af; af.u4 = raw;
            acc6[mt] = __builtin_amdgcn_mfma_f32_16x16x32_bf16(af.v, bfr, acc6[mt], 0, 0, 0);
        }
    }
    // C layout: row(px)=q*4+reg, col(j)=m. Transpose via LDS (per-wave region).
    float bias = (m < 6) ? obias[m] : 0.f;
#pragma unroll
    for (int mt = 0; mt < 2; ++mt)
#pragma unroll
        for (int reg = 0; reg < 4; ++reg)
            if (m < 6) offT[(w * 32 + mt * 16 + q * 4 + reg) * 9 + m] = acc6[mt][reg] + bias;
    __syncthreads();

    // ---------- phase 2: deformable strip conv ----------
    f32x4 acc[2][4];
#pragma unroll
    for (int mt = 0; mt < 2; ++mt)
#pragma unroll
        for (int nt = 0; nt < 4; ++nt) acc[mt][nt] = (f32x4){0.f, 0.f, 0.f, 0.f};

#pragma unroll
    for (int pk = 0; pk < 6; ++pk) {
        const int ph = pk / 3;
        const int k  = pk % 3;

        float wA[2], wB[2];
        const unsigned short *pA[2], *pB[2];
#pragma unroll
        for (int mt = 0; mt < 2; ++mt) {
            const int xs = x0w + mt * 16 + m;
            float o1 = offT[(w * 32 + mt * 16 + m) * 9 + pk];
            int idxA, idxB;
            if (ph == 0) {
                // horizontal: py = y + off (frac), px = xs + k - 1 (int)
                float py  = (float)y + o1;
                float y0f = floorf(py);
                float wy  = py - y0f;
                int   yi  = (int)y0f;
                bool v0 = (yi >= 0) && (yi <= HH - 1);
                bool v1 = (yi + 1 >= 0) && (yi + 1 <= HH - 1);
                int  pxx = xs + k - 1;
                bool pv  = (pxx >= 0) && (pxx <= WW - 1);
                wA[mt] = (pv && v0) ? (1.f - wy) : 0.f;
                wB[mt] = (pv && v1) ? wy : 0.f;
                int ra = min(max(yi, 0), HH - 1);
                int rb = min(max(yi + 1, 0), HH - 1);
                int ca = min(max(pxx, 0), WW - 1);
                idxA = ra * WW + ca;
                idxB = rb * WW + ca;
            } else {
                // vertical: py = y + k - 1 (int), px = xs + off (frac)
                float pxf = (float)xs + o1;
                float x0f = floorf(pxf);
                float wx  = pxf - x0f;
                int   xi  = (int)x0f;
                bool v0 = (xi >= 0) && (xi <= WW - 1);
                bool v1 = (xi + 1 >= 0) && (xi + 1 <= WW - 1);
                int  py = y + k - 1;
                bool pv = (py >= 0) && (py <= HH - 1);
                wA[mt] = (pv && v0) ? (1.f - wx) : 0.f;
                wB[mt] = (pv && v1) ? wx : 0.f;
                int ra  = min(max(py, 0), HH - 1);
                int ca  = min(max(xi, 0), WW - 1);
                int cb2 = min(max(xi + 1, 0), WW - 1);
                idxA = ra * WW + ca;
                idxB = ra * WW + cb2;
            }
            pA[mt] = xtb + (size_t)idxA * 64;
            pB[mt] = xtb + (size_t)idxB * 64;
        }

#pragma unroll
        for (int kc = 0; kc < 2; ++kc) {
            const int coff = kc * 32 + q * 8;
            bf16x8 afrag[2];
#pragma unroll
            for (int mt = 0; mt < 2; ++mt) {
                union { uint4 u4; unsigned short us[8]; bf16x8 v; } ua, ub, uf;
                ua.u4 = *(const uint4*)(pA[mt] + coff);
                ub.u4 = *(const uint4*)(pB[mt] + coff);
#pragma unroll
                for (int j = 0; j < 8; ++j) {
                    float v = wA[mt] * bf2f(ua.us[j]) + wB[mt] * bf2f(ub.us[j]);
                    uf.us[j] = f2bf(v);
                }
                afrag[mt] = uf.v;
            }
#pragma unroll
            for (int nt = 0; nt < 4; ++nt) {
                bf16x8 bfr = *(const bf16x8*)&Bf[(((pk * 2 + kc) * 4 + nt) * 64 + lane) * 8];
#pragma unroll
                for (int mt = 0; mt < 2; ++mt)
                    acc[mt][nt] = __builtin_amdgcn_mfma_f32_16x16x32_bf16(
                        afrag[mt], bfr, acc[mt][nt], 0, 0, 0);
            }
        }
    }

    // ---------- epilogue: C row(px)=q*4+reg, col(o)=m ----------
#pragma unroll
    for (int mt = 0; mt < 2; ++mt)
#pragma unroll
        for (int nt = 0; nt < 4; ++nt) {
            int o = nt * 16 + m;
            float* op = out + ((size_t)(b * COUT + o) * HH + y) * WW + x0w + mt * 16 + q * 4;
            *(f32x4*)op = acc[mt][nt];
        }
}

extern "C" void kernel_launch(void* const* d_in, const int* in_sizes, int n_in,
                              void* d_out, int out_size, void* d_ws, size_t ws_size,
                              hipStream_t stream) {
    const float* x     = (const float*)d_in[0];
    const float* ow    = (const float*)d_in[1];
    const float* obias = (const float*)d_in[2];
    const float* wh    = (const float*)d_in[3];
    const float* wv    = (const float*)d_in[4];
    float* out = (float*)d_out;

    char* ws = (char*)d_ws;
    unsigned short* xT  = (unsigned short*)(ws + XT_OFF);
    unsigned short* Bf  = (unsigned short*)(ws + BF_OFF);
    unsigned short* OBf = (unsigned short*)(ws + OBF_OFF);

    prep_kernel<<<dim3(132), dim3(256), 0, stream>>>(ow, wh, wv, Bf, OBf);
    repack_kernel<<<dim3(1024), dim3(256), 0, stream>>>(x, xT);
    // 1024 blocks = y(128) x b(8); b = blk&7 pins batch -> XCD (L2 locality)
    fused_kernel<<<dim3(1024), dim3(256), 0, stream>>>(xT, obias, Bf, OBf, out);
}